// Round 1
// baseline (46.471 us; speedup 1.0000x reference)
//
#include <hip/hip_runtime.h>
#include <math.h>

// Problem constants (match reference)
constexpr int   T_DIM = 4096;
constexpr int   NC    = 10;
constexpr int   NTHR  = 1024;          // 16 waves/block, one block per batch row
constexpr int   NWAVE = NTHR / 64;

constexpr float EPS_C   = 0.2f;
constexpr float ALPHA_C = 0.5f;
constexpr float GAMMA_C = 1e-4f;
constexpr float MU_C    = 8e-4f;

__global__ __launch_bounds__(NTHR) void mbs_kernel(
    const float* __restrict__ scores,
    const float* __restrict__ attw,
    const int*   __restrict__ seqlen,
    float*       __restrict__ out,
    int B)
{
    __shared__ float s_lds[T_DIM];
    __shared__ float a_lds[T_DIM];
    __shared__ float red_mx[NWAVE];
    __shared__ float red_mn[NWAVE];
    __shared__ float red_sum[NWAVE][8];
    __shared__ float sh_theta;

    const int tid  = threadIdx.x;
    const int lane = tid & 63;
    const int wid  = tid >> 6;
    const int b    = blockIdx.x;
    const int slen = seqlen[b];
    const bool pos = b < (B >> 1);
    const int t0   = tid * 4;

    // ---------- pass 1: channel mean into LDS, masked max/min of A ----------
    float4 s4 = make_float4(0.f, 0.f, 0.f, 0.f);
    float4 a4 = make_float4(0.f, 0.f, 0.f, 0.f);
    const size_t rowbase = (size_t)b * NC * T_DIM + t0;
#pragma unroll
    for (int c = 0; c < NC; ++c) {
        const float4 sv = *reinterpret_cast<const float4*>(scores + rowbase + (size_t)c * T_DIM);
        const float4 av = *reinterpret_cast<const float4*>(attw   + rowbase + (size_t)c * T_DIM);
        s4.x += sv.x; s4.y += sv.y; s4.z += sv.z; s4.w += sv.w;
        a4.x += av.x; a4.y += av.y; a4.z += av.z; a4.w += av.w;
    }
    const float invNC = 1.0f / (float)NC;
    s4.x *= invNC; s4.y *= invNC; s4.z *= invNC; s4.w *= invNC;
    a4.x *= invNC; a4.y *= invNC; a4.z *= invNC; a4.w *= invNC;

    reinterpret_cast<float4*>(s_lds)[tid] = s4;
    reinterpret_cast<float4*>(a_lds)[tid] = a4;

    const float sarr[4] = {s4.x, s4.y, s4.z, s4.w};
    const float aarr[4] = {a4.x, a4.y, a4.z, a4.w};

    float amax = -INFINITY, amin = INFINITY;
#pragma unroll
    for (int j = 0; j < 4; ++j) {
        if (t0 + j < slen) {
            amax = fmaxf(amax, aarr[j]);
            amin = fminf(amin, aarr[j]);
        }
    }
#pragma unroll
    for (int off = 32; off; off >>= 1) {
        amax = fmaxf(amax, __shfl_down(amax, off, 64));
        amin = fminf(amin, __shfl_down(amin, off, 64));
    }
    if (lane == 0) { red_mx[wid] = amax; red_mn[wid] = amin; }
    __syncthreads();   // also publishes s_lds/a_lds for pass 2 neighbor reads
    if (tid == 0) {
        float mx = red_mx[0], mn = red_mn[0];
#pragma unroll
        for (int w = 1; w < NWAVE; ++w) {
            mx = fmaxf(mx, red_mx[w]);
            mn = fminf(mn, red_mn[w]);
        }
        sh_theta = (mx - mn) * EPS_C + mn;
    }
    __syncthreads();
    const float theta = sh_theta;

    // ---------- pass 2: all reductions from registers (+LDS neighbor) ----------
    // v0=log(S) bce, v1=log(SA) bce, v2=sup bce(S), v3=sup bce(SA),
    // v4=sum|A| (pos rows), v5=LG sum (rows 127/255), v6=smooth, v7=spread
    float v0 = 0.f, v1 = 0.f, v2 = 0.f, v3 = 0.f,
          v4 = 0.f, v5 = 0.f, v6 = 0.f, v7 = 0.f;
    const bool isLG = (b == (B >> 1) - 1) || (b == B - 1);

#pragma unroll
    for (int j = 0; j < 4; ++j) {
        const int t   = t0 + j;
        const float s  = sarr[j];
        const float a  = aarr[j];
        const float sa = s * a;
        if (t < slen) {
            const bool sup = a < theta;
            if (pos) {
                const float ls  = fmaxf(logf(s),  -100.0f);
                const float lsa = fmaxf(logf(sa), -100.0f);
                v0 += ls;
                v1 += lsa;
                v2 += sup ? ls  : -100.0f;   // log(0) clamped
                v3 += sup ? lsa : -100.0f;
                v4 += fabsf(a);
                if (isLG) v5 += (a - s) * (a - s);
            } else {
                const float ls  = fmaxf(logf(1.0f - s),  -100.0f);
                const float lsa = fmaxf(logf(1.0f - sa), -100.0f);
                v0 += ls;
                v1 += lsa;
                if (sup) { v2 += ls; v3 += lsa; }  // !sup -> log(1-0)=0
                if (isLG) v5 += a * a;
            }
            v7 += s + sa;
        }
        if (t < slen - 1) {   // slen <= T so t+1 <= T-1 is safe
            const float s2 = (j < 3) ? sarr[j + 1] : s_lds[t + 1];
            const float a2 = (j < 3) ? aarr[j + 1] : a_lds[t + 1];
            const float ds  = s  - s2;
            const float dsa = sa - s2 * a2;
            v6 += ds * ds + dsa * dsa;
        }
    }

    // ---------- block reduce 8 sums ----------
    float vals[8] = {v0, v1, v2, v3, v4, v5, v6, v7};
#pragma unroll
    for (int k = 0; k < 8; ++k) {
#pragma unroll
        for (int off = 32; off; off >>= 1)
            vals[k] += __shfl_down(vals[k], off, 64);
    }
    if (lane == 0) {
#pragma unroll
        for (int k = 0; k < 8; ++k) red_sum[wid][k] = vals[k];
    }
    __syncthreads();

    if (tid == 0) {
        float tot[8];
#pragma unroll
        for (int k = 0; k < 8; ++k) tot[k] = 0.f;
        for (int w = 0; w < NWAVE; ++w)
#pragma unroll
            for (int k = 0; k < 8; ++k) tot[k] += red_sum[w][k];

        const float inv_slen = 1.0f / (float)slen;
        const float invB2    = 2.0f / (float)B;   // 1/128

        atomicAdd(out + 0, ALPHA_C          * (-tot[0] * inv_slen) * invB2);
        atomicAdd(out + 1, ALPHA_C          * (-tot[1] * inv_slen) * invB2);
        atomicAdd(out + 2, (1.0f - ALPHA_C) * (-tot[2] * inv_slen) * invB2);
        atomicAdd(out + 3, (1.0f - ALPHA_C) * (-tot[3] * inv_slen) * invB2);
        if (pos)               atomicAdd(out + 4, GAMMA_C * tot[4] * invB2);
        if (b == B - 1)        atomicAdd(out + 5, tot[5] * inv_slen);   // LG_0 (row 255)
        if (b == (B >> 1) - 1) atomicAdd(out + 6, tot[5] * inv_slen);   // LG_1 (row 127)
        atomicAdd(out + 7, MU_C * tot[6] * invB2);
        atomicAdd(out + 8, tot[7] * invB2);
    }
}

extern "C" void kernel_launch(void* const* d_in, const int* in_sizes, int n_in,
                              void* d_out, int out_size, void* d_ws, size_t ws_size,
                              hipStream_t stream) {
    const float* scores = (const float*)d_in[0];
    const float* attw   = (const float*)d_in[1];
    // d_in[2] = label (unused: reference splits by fixed B/2)
    const int*   seqlen = (const int*)d_in[3];
    const int B = in_sizes[2];

    hipMemsetAsync(d_out, 0, out_size * sizeof(float), stream);
    mbs_kernel<<<dim3(B), dim3(NTHR), 0, stream>>>(scores, attw, seqlen,
                                                   (float*)d_out, B);
}

// Round 2
// 19.554 us; speedup vs baseline: 2.3765x; 2.3765x over previous
//
#include <hip/hip_runtime.h>
#include <math.h>

// Problem constants (match reference)
constexpr int   T_DIM = 4096;
constexpr int   NC    = 10;
constexpr int   NTHR  = 1024;          // 16 waves/block, one block per batch row
constexpr int   NWAVE = NTHR / 64;
constexpr int   PSTRIDE = 16;          // floats per partial-row in d_ws

constexpr float EPS_C   = 0.2f;
constexpr float ALPHA_C = 0.5f;
constexpr float GAMMA_C = 1e-4f;
constexpr float MU_C    = 8e-4f;

__global__ __launch_bounds__(NTHR) void mbs_pass1(
    const float* __restrict__ scores,
    const float* __restrict__ attw,
    const int*   __restrict__ seqlen,
    float*       __restrict__ part,    // [B][PSTRIDE] per-block contributions
    int B)
{
    __shared__ float s_lds[T_DIM];
    __shared__ float a_lds[T_DIM];
    __shared__ float red_mx[NWAVE];
    __shared__ float red_mn[NWAVE];
    __shared__ float red_sum[NWAVE][8];
    __shared__ float sh_theta;

    const int tid  = threadIdx.x;
    const int lane = tid & 63;
    const int wid  = tid >> 6;
    const int b    = blockIdx.x;
    const int slen = seqlen[b];
    const bool pos = b < (B >> 1);
    const int t0   = tid * 4;
    const bool active = t0 < slen;     // elements t>=slen are never used by ANY term

    // ---------- pass 1: channel mean into LDS, masked max/min of A ----------
    float4 s4 = make_float4(0.f, 0.f, 0.f, 0.f);
    float4 a4 = make_float4(0.f, 0.f, 0.f, 0.f);
    if (active) {
        const size_t rowbase = (size_t)b * NC * T_DIM + t0;
#pragma unroll
        for (int c = 0; c < NC; ++c) {
            const float4 sv = *reinterpret_cast<const float4*>(scores + rowbase + (size_t)c * T_DIM);
            const float4 av = *reinterpret_cast<const float4*>(attw   + rowbase + (size_t)c * T_DIM);
            s4.x += sv.x; s4.y += sv.y; s4.z += sv.z; s4.w += sv.w;
            a4.x += av.x; a4.y += av.y; a4.z += av.z; a4.w += av.w;
        }
        const float invNC = 1.0f / (float)NC;
        s4.x *= invNC; s4.y *= invNC; s4.z *= invNC; s4.w *= invNC;
        a4.x *= invNC; a4.y *= invNC; a4.z *= invNC; a4.w *= invNC;

        reinterpret_cast<float4*>(s_lds)[tid] = s4;
        reinterpret_cast<float4*>(a_lds)[tid] = a4;
    }

    const float sarr[4] = {s4.x, s4.y, s4.z, s4.w};
    const float aarr[4] = {a4.x, a4.y, a4.z, a4.w};

    float amax = -INFINITY, amin = INFINITY;
    if (active) {
#pragma unroll
        for (int j = 0; j < 4; ++j) {
            if (t0 + j < slen) {
                amax = fmaxf(amax, aarr[j]);
                amin = fminf(amin, aarr[j]);
            }
        }
    }
#pragma unroll
    for (int off = 32; off; off >>= 1) {
        amax = fmaxf(amax, __shfl_down(amax, off, 64));
        amin = fminf(amin, __shfl_down(amin, off, 64));
    }
    if (lane == 0) { red_mx[wid] = amax; red_mn[wid] = amin; }
    __syncthreads();   // also publishes s_lds/a_lds for pass-2 neighbor reads
    if (tid == 0) {
        float mx = red_mx[0], mn = red_mn[0];
#pragma unroll
        for (int w = 1; w < NWAVE; ++w) {
            mx = fmaxf(mx, red_mx[w]);
            mn = fminf(mn, red_mn[w]);
        }
        sh_theta = (mx - mn) * EPS_C + mn;
    }
    __syncthreads();
    const float theta = sh_theta;

    // ---------- pass 2: all reductions from registers (+LDS neighbor) ----------
    // v0=log(S) bce, v1=log(SA) bce, v2=sup bce(S), v3=sup bce(SA),
    // v4=sum|A| (pos rows), v5=LG sum (rows B/2-1, B-1), v6=smooth, v7=spread
    float v0 = 0.f, v1 = 0.f, v2 = 0.f, v3 = 0.f,
          v4 = 0.f, v5 = 0.f, v6 = 0.f, v7 = 0.f;
    const bool isLG = (b == (B >> 1) - 1) || (b == B - 1);

    if (active) {
#pragma unroll
        for (int j = 0; j < 4; ++j) {
            const int t   = t0 + j;
            const float s  = sarr[j];
            const float a  = aarr[j];
            const float sa = s * a;
            if (t < slen) {
                const bool sup = a < theta;
                if (pos) {
                    const float ls  = fmaxf(__logf(s),  -100.0f);
                    const float lsa = fmaxf(__logf(sa), -100.0f);
                    v0 += ls;
                    v1 += lsa;
                    v2 += sup ? ls  : -100.0f;   // log(0) clamped
                    v3 += sup ? lsa : -100.0f;
                    v4 += fabsf(a);
                    if (isLG) v5 += (a - s) * (a - s);
                } else {
                    const float ls  = fmaxf(__logf(1.0f - s),  -100.0f);
                    const float lsa = fmaxf(__logf(1.0f - sa), -100.0f);
                    v0 += ls;
                    v1 += lsa;
                    if (sup) { v2 += ls; v3 += lsa; }  // !sup -> log(1-0)=0
                    if (isLG) v5 += a * a;
                }
                v7 += s + sa;
            }
            if (t < slen - 1) {   // t+1 < slen, owner thread of t+1 was active
                const float s2 = (j < 3) ? sarr[j + 1] : s_lds[t + 1];
                const float a2 = (j < 3) ? aarr[j + 1] : a_lds[t + 1];
                const float ds  = s  - s2;
                const float dsa = sa - s2 * a2;
                v6 += ds * ds + dsa * dsa;
            }
        }
    }

    // ---------- block reduce 8 sums ----------
    float vals[8] = {v0, v1, v2, v3, v4, v5, v6, v7};
#pragma unroll
    for (int k = 0; k < 8; ++k) {
#pragma unroll
        for (int off = 32; off; off >>= 1)
            vals[k] += __shfl_down(vals[k], off, 64);
    }
    if (lane == 0) {
#pragma unroll
        for (int k = 0; k < 8; ++k) red_sum[wid][k] = vals[k];
    }
    __syncthreads();

    if (tid == 0) {
        float tot[8];
#pragma unroll
        for (int k = 0; k < 8; ++k) tot[k] = 0.f;
        for (int w = 0; w < NWAVE; ++w)
#pragma unroll
            for (int k = 0; k < 8; ++k) tot[k] += red_sum[w][k];

        const float inv_slen = 1.0f / (float)slen;
        const float invB2    = 2.0f / (float)B;   // 1/128

        float* p = part + (size_t)b * PSTRIDE;
        p[0] = ALPHA_C          * (-tot[0] * inv_slen) * invB2;
        p[1] = ALPHA_C          * (-tot[1] * inv_slen) * invB2;
        p[2] = (1.0f - ALPHA_C) * (-tot[2] * inv_slen) * invB2;
        p[3] = (1.0f - ALPHA_C) * (-tot[3] * inv_slen) * invB2;
        p[4] = pos ? (GAMMA_C * tot[4] * invB2) : 0.0f;
        p[5] = (b == B - 1)        ? tot[5] * inv_slen : 0.0f;  // LG_0 (row B-1)
        p[6] = (b == (B >> 1) - 1) ? tot[5] * inv_slen : 0.0f;  // LG_1 (row B/2-1)
        p[7] = MU_C * tot[6] * invB2;
        p[8] = tot[7] * invB2;
    }
}

__global__ __launch_bounds__(64) void mbs_pass2(
    const float* __restrict__ part,
    float*       __restrict__ out,
    int B)
{
    float acc[9];
#pragma unroll
    for (int k = 0; k < 9; ++k) acc[k] = 0.f;
    for (int r = (int)threadIdx.x; r < B; r += 64) {
        const float* p = part + (size_t)r * PSTRIDE;
#pragma unroll
        for (int k = 0; k < 9; ++k) acc[k] += p[k];
    }
#pragma unroll
    for (int k = 0; k < 9; ++k) {
#pragma unroll
        for (int off = 32; off; off >>= 1)
            acc[k] += __shfl_down(acc[k], off, 64);
    }
    if (threadIdx.x == 0) {
#pragma unroll
        for (int k = 0; k < 9; ++k) out[k] = acc[k];
    }
}

extern "C" void kernel_launch(void* const* d_in, const int* in_sizes, int n_in,
                              void* d_out, int out_size, void* d_ws, size_t ws_size,
                              hipStream_t stream) {
    const float* scores = (const float*)d_in[0];
    const float* attw   = (const float*)d_in[1];
    // d_in[2] = label (unused: reference splits by fixed B/2)
    const int*   seqlen = (const int*)d_in[3];
    const int B = in_sizes[2];

    float* part = (float*)d_ws;   // B * PSTRIDE floats, rewritten every launch

    mbs_pass1<<<dim3(B), dim3(NTHR), 0, stream>>>(scores, attw, seqlen, part, B);
    mbs_pass2<<<dim3(1), dim3(64), 0, stream>>>(part, (float*)d_out, B);
}